// Round 4
// baseline (7004.852 us; speedup 1.0000x reference)
//
#include <hip/hip_runtime.h>
#include <hip/hip_bf16.h>
#include <stdint.h>
#include <stddef.h>

// LSTM: INPUT=512, HIDDEN=1024, BATCH=64, SEQ=512.
// Persistent kernel, TAG-IN-DATA sync (no flags, no producer ack):
//   - h published as (tag<<16)|bf16 dwords, tag = step t (exact freshness check:
//     0xAAAA poison and stale tag t-2 both mismatch). Producer: 2 fire-and-forget
//     8B agent stores per publishing lane. Consumer: polls the data directly,
//     re-loading only stale qwords. One MALL hop instead of four.
//   - x-side GEMM (xg) computed one step AHEAD into registers, off the
//     recurrent critical path (producers' slack window).
//   - Weights pinned in registers/AGPRs (48 x short8 per wave).
#define ISZ   512
#define HSZ   1024
#define NBAT  64
#define SEQL  512

typedef __attribute__((ext_vector_type(8))) short  short8;   // 8 x bf16 (4 VGPR)
typedef __attribute__((ext_vector_type(4))) float  floatx4;  // MFMA accumulator

__device__ __forceinline__ unsigned short f2bf(float f){     // RNE f32 -> bf16
  unsigned int u = __float_as_uint(f);
  u += 0x7FFFu + ((u >> 16) & 1u);
  return (unsigned short)(u >> 16);
}
__device__ __forceinline__ float sigf(float x){ return 1.0f / (1.0f + __expf(-x)); }
__device__ __forceinline__ float tanh_(float x){ return 2.0f / (1.0f + __expf(-2.0f * x)) - 1.0f; }
__device__ __forceinline__ float sel4(int idx, float a0, float a1, float a2, float a3){
  float r01 = (idx & 1) ? a1 : a0;
  float r23 = (idx & 1) ? a3 : a2;
  return (idx & 2) ? r23 : r01;
}

// ---------------- x f32 -> bf16 ----------------
__global__ __launch_bounds__(256) void k_convert_x(const float* __restrict__ x,
                                                   unsigned short* __restrict__ xb){
  int i = (blockIdx.x * 256 + threadIdx.x) * 8;                      // 8192*256*8 == 64*512*512
  const float4* p = (const float4*)(x + i);
  float4 a = p[0], b = p[1];
  unsigned int w0 = (unsigned int)f2bf(a.x) | ((unsigned int)f2bf(a.y) << 16);
  unsigned int w1 = (unsigned int)f2bf(a.z) | ((unsigned int)f2bf(a.w) << 16);
  unsigned int w2 = (unsigned int)f2bf(b.x) | ((unsigned int)f2bf(b.y) << 16);
  unsigned int w3 = (unsigned int)f2bf(b.z) | ((unsigned int)f2bf(b.w) << 16);
  *(uint4*)(xb + i) = make_uint4(w0, w1, w2, w3);
}

// ---------------- pack W_h/W_x into per-(cg,wave,chunk,lane) B-fragments ----------------
__global__ __launch_bounds__(256) void k_pack_w(const float* __restrict__ Wx,
                                                const float* __restrict__ Wh,
                                                unsigned short* __restrict__ pw){
  int id = blockIdx.x * 256 + threadIdx.x;     // < 786432 = 64*4*48*64
  int lane = id & 63;
  int ch   = (id >> 6) % 48;
  int t2   = (id >> 6) / 48;                   // cg*4 + wv
  int wv = t2 & 3, cg = t2 >> 2;
  int nn = lane & 15, kgrp = lane >> 4;
  int g = nn >> 2, hcl = nn & 3;
  int colh = cg * 16 + wv * 4 + hcl;           // 0..1023
  unsigned short o[8];
  if (ch < 32){
    int k0 = ch * 32 + kgrp * 8;
#pragma unroll
    for (int j = 0; j < 8; ++j) o[j] = f2bf(Wh[(g * 1024 + k0 + j) * 1024 + colh]);
  } else {
    int k0 = (ch - 32) * 32 + kgrp * 8;
#pragma unroll
    for (int j = 0; j < 8; ++j) o[j] = f2bf(Wx[(g * 512 + k0 + j) * 1024 + colh]);
  }
  unsigned int w0 = (unsigned int)o[0] | ((unsigned int)o[1] << 16);
  unsigned int w1 = (unsigned int)o[2] | ((unsigned int)o[3] << 16);
  unsigned int w2 = (unsigned int)o[4] | ((unsigned int)o[5] << 16);
  unsigned int w3 = (unsigned int)o[6] | ((unsigned int)o[7] << 16);
  ((uint4*)pw)[id] = make_uint4(w0, w1, w2, w3);
}

// ---------------- persistent LSTM scan ----------------
__global__ __launch_bounds__(256, 1) void k_scan(const unsigned short* __restrict__ pw,
                                                 const unsigned short* __restrict__ xb,
                                                 const float* __restrict__ bias,
                                                 unsigned long long* __restrict__ hq,  // [2][64][1024] tagged dwords (as qwords)
                                                 float* __restrict__ out){             // h[64][1024] ++ c[64][1024]
  __shared__ __align__(16) char lds_h[16 * 2048];        // 16 batches x 1024 bf16, XOR-swizzled
  __shared__ __align__(16) char lds_x[16 * 1024];        // 16 batches x 512 bf16, XOR-swizzled

  const int wg = blockIdx.x;       // 0..255
  const int bg = wg >> 6;          // batch group 0..3 (independent chains)
  const int cg = wg & 63;          // col group 0..63
  const int tid = threadIdx.x;
  const int wv = tid >> 6;         // wave 0..3
  const int lane = tid & 63;
  const int b0 = bg * 16;

  // ---- persistent weights in registers, PINNED
  short8 bh[32], bx[16];
  {
    const uint4* base = (const uint4*)pw + (cg * 4 + wv) * 48 * 64 + lane;
#pragma unroll
    for (int c = 0; c < 32; ++c) bh[c] = *(const short8*)(base + c * 64);
#pragma unroll
    for (int c = 0; c < 16; ++c) bx[c] = *(const short8*)(base + (32 + c) * 64);
  }
#pragma unroll
  for (int c = 0; c < 32; ++c) asm volatile("" : "+v"(bh[c]));
#pragma unroll
  for (int c = 0; c < 16; ++c) asm volatile("" : "+v"(bx[c]));

  const int nn = lane & 15;        // MFMA col index n
  const int G  = nn >> 2;          // gate group (0=i,1=f,2=g,3=o)
  const int hc = nn & 3;           // h-col within wave
  const int kgrp = lane >> 4;      // k-group 0..3
  const int colh = cg * 16 + wv * 4 + hc;    // global h-col 0..1023
  const float b_i = bias[0 * HSZ + colh];
  const float b_f = bias[1 * HSZ + colh];
  const float b_g = bias[2 * HSZ + colh];
  const float b_o = bias[3 * HSZ + colh];

  // A-fragment LDS read bases
  const int arow = nn;                        // batch row 0..15
  const int swz  = (arow & 7) << 4;
  const int hb0  = arow * 2048 + ((kgrp * 16 +  0) ^ swz);
  const int hb1  = arow * 2048 + ((kgrp * 16 + 64) ^ swz);
  const int xq0  = arow * 1024 + ((kgrp * 16 +  0) ^ swz);
  const int xq1  = arow * 1024 + ((kgrp * 16 + 64) ^ swz);

  // consumer poll geometry: thread covers row (tid>>4), 64 cols starting at (tid&15)*64
  const int prow = tid >> 4;
  const int pcb  = (tid & 15) * 64;
  const int pswz = (prow & 7) << 4;

  float cst[4] = {0.f, 0.f, 0.f, 0.f};        // c-state: rows kgrp*4+r, col hc
  floatx4 xp0, xp1;                           // parked xg(t) (x-side gate partials)

  // ---- prologue: xg(0)
  {
#pragma unroll
    for (int i = 0; i < 4; ++i){
      int ch = i * 256 + tid;
      int row = ch >> 6, o16 = ch & 63;
      uint4 v = *(const uint4*)((const char*)xb + (((size_t)(b0 + row) * SEQL + 0) * ISZ) * 2 + o16 * 16);
      *(uint4*)(lds_x + row * 1024 + ((o16 * 16) ^ ((row & 7) << 4))) = v;
    }
    __syncthreads();
    floatx4 a0v = {0.f,0.f,0.f,0.f}, a1v = {0.f,0.f,0.f,0.f};
#pragma unroll
    for (int q = 0; q < 8; ++q){
      short8 a0 = *(const short8*)(lds_x + xq0 + q * 128);
      a0v = __builtin_amdgcn_mfma_f32_16x16x32_bf16(a0, bx[2 * q], a0v, 0, 0, 0);
      short8 a1 = *(const short8*)(lds_x + xq1 + q * 128);
      a1v = __builtin_amdgcn_mfma_f32_16x16x32_bf16(a1, bx[2 * q + 1], a1v, 0, 0, 0);
    }
    xp0 = a0v; xp1 = a1v;
    __syncthreads();
  }

#pragma unroll 1
  for (int t = 0; t < SEQL; ++t){
    // ---- issue x loads for t+1 immediately (full-step prefetch window)
    const int tn = (t + 1 < SEQL) ? (t + 1) : (SEQL - 1);
    uint4 xr[4]; int xdst[4];
#pragma unroll
    for (int i = 0; i < 4; ++i){
      int ch = i * 256 + tid;
      int row = ch >> 6, o16 = ch & 63;
      xr[i] = *(const uint4*)((const char*)xb + (((size_t)(b0 + row) * SEQL + tn) * ISZ) * 2 + o16 * 16);
      xdst[i] = row * 1024 + ((o16 * 16) ^ ((row & 7) << 4));
    }

    // ---- poll h(t-1) directly (tag-validated), stage into lds_h
    if (t > 0){
      const unsigned int tg = (unsigned int)(t - 1);
      unsigned long long* base = hq + ((size_t)(((t - 1) & 1) * 64 + b0 + prow)) * 512 + (pcb >> 1);
      unsigned long long vals[32];
      unsigned int pend = 0xFFFFFFFFu;
      while (pend){
#pragma unroll
        for (int q = 0; q < 32; ++q)
          if ((pend >> q) & 1u)
            vals[q] = __hip_atomic_load(base + q, __ATOMIC_RELAXED, __HIP_MEMORY_SCOPE_AGENT);
        unsigned int np = 0;
#pragma unroll
        for (int q = 0; q < 32; ++q){
          if ((pend >> q) & 1u){
            unsigned int d0 = (unsigned int)vals[q];
            unsigned int d1 = (unsigned int)(vals[q] >> 32);
            if ((((d0 >> 16) ^ tg) | ((d1 >> 16) ^ tg)) == 0u){
              unsigned int packed = (d0 & 0xFFFFu) | (d1 << 16);
              *(unsigned int*)(lds_h + prow * 2048 + (((pcb + 2 * q) * 2) ^ pswz)) = packed;
            } else np |= (1u << q);
          }
        }
        pend = np;
      }
      __syncthreads();   // barrier H
    }

    // ---- gates: acc = parked xg(t); accumulate h-GEMM (K=1024)
    floatx4 acc0 = xp0, acc1 = xp1;
    if (t > 0){
#pragma unroll
      for (int q = 0; q < 16; ++q){
        short8 a0 = *(const short8*)(lds_h + hb0 + q * 128);
        acc0 = __builtin_amdgcn_mfma_f32_16x16x32_bf16(a0, bh[2 * q], acc0, 0, 0, 0);
        short8 a1 = *(const short8*)(lds_h + hb1 + q * 128);
        acc1 = __builtin_amdgcn_mfma_f32_16x16x32_bf16(a1, bh[2 * q + 1], acc1, 0, 0, 0);
      }
    }

    // ---- elementwise combine
    float hvv[4];
#pragma unroll
    for (int r = 0; r < 4; ++r){
      float own = acc0[r] + acc1[r];
      float s4  = __shfl_xor(own, 4);
      float s8  = __shfl_xor(own, 8);
      float s12 = __shfl_xor(own, 12);
      float pi = sel4(G,     own, s4, s8, s12) + b_i;
      float pf = sel4(G ^ 1, own, s4, s8, s12) + b_f;
      float pg = sel4(G ^ 2, own, s4, s8, s12) + b_g;
      float po = sel4(G ^ 3, own, s4, s8, s12) + b_o;
      float iv = sigf(pi), fv = sigf(pf), gv = tanh_(pg), ov = sigf(po);
      float cn = fv * cst[r] + iv * gv;
      cst[r] = cn;
      hvv[r] = ov * tanh_(cn);
      if (G == 0 && t == SEQL - 1){
        int gb = b0 + kgrp * 4 + r;
        out[gb * HSZ + colh] = hvv[r];                 // h_T
        out[NBAT * HSZ + gb * HSZ + colh] = cn;        // c_T
      }
    }

    // ---- publish h(t): 4x4 shfl transpose, then 2 tagged fire-and-forget 8B stores/lane
    if (G == 0){
      float a0 = hvv[0], a1 = hvv[1], a2 = hvv[2], a3 = hvv[3];
      float s0 = __shfl_xor(a1, 1), s1 = __shfl_xor(a0, 1);
      float s2 = __shfl_xor(a3, 1), s3 = __shfl_xor(a2, 1);
      bool o1 = (nn & 1);
      float t0 = o1 ? s0 : a0,  t1 = o1 ? a1 : s1;
      float t2 = o1 ? s2 : a2,  t3 = o1 ? a3 : s3;
      float u0 = __shfl_xor(t2, 2), u1 = __shfl_xor(t3, 2);
      float u2 = __shfl_xor(t0, 2), u3 = __shfl_xor(t1, 2);
      bool o2 = (nn & 2);
      float w0 = o2 ? u0 : t0,  w1 = o2 ? u1 : t1;
      float w2 = o2 ? t2 : u2,  w3 = o2 ? t3 : u3;
      // lane nn holds row kgrp*4+nn, cols (cg*16+wv*4)+0..3
      unsigned int tagw = ((unsigned int)t) << 16;
      unsigned int p0 = (unsigned int)f2bf(w0) | tagw;
      unsigned int p1 = (unsigned int)f2bf(w1) | tagw;
      unsigned int p2 = (unsigned int)f2bf(w2) | tagw;
      unsigned int p3 = (unsigned int)f2bf(w3) | tagw;
      unsigned long long v0 = (unsigned long long)p0 | ((unsigned long long)p1 << 32);
      unsigned long long v1 = (unsigned long long)p2 | ((unsigned long long)p3 << 32);
      int row = kgrp * 4 + nn;
      size_t off = ((size_t)((t & 1) * 64 + b0 + row)) * 512 + cg * 8 + wv * 2;
      __hip_atomic_store(hq + off,     v0, __ATOMIC_RELAXED, __HIP_MEMORY_SCOPE_AGENT);
      __hip_atomic_store(hq + off + 1, v1, __ATOMIC_RELAXED, __HIP_MEMORY_SCOPE_AGENT);
    }

    // ---- x side for t+1 (slack window): stage + GEMM into parked regs
#pragma unroll
    for (int i = 0; i < 4; ++i) *(uint4*)(lds_x + xdst[i]) = xr[i];
    __syncthreads();   // barrier X
    {
      floatx4 a0v = {0.f,0.f,0.f,0.f}, a1v = {0.f,0.f,0.f,0.f};
#pragma unroll
      for (int q = 0; q < 8; ++q){
        short8 a0 = *(const short8*)(lds_x + xq0 + q * 128);
        a0v = __builtin_amdgcn_mfma_f32_16x16x32_bf16(a0, bx[2 * q], a0v, 0, 0, 0);
        short8 a1 = *(const short8*)(lds_x + xq1 + q * 128);
        a1v = __builtin_amdgcn_mfma_f32_16x16x32_bf16(a1, bx[2 * q + 1], a1v, 0, 0, 0);
      }
      xp0 = a0v; xp1 = a1v;
    }
    __syncthreads();   // barrier Z (protects lds_x and lds_h reuse next iter)
  }
}

extern "C" void kernel_launch(void* const* d_in, const int* in_sizes, int n_in,
                              void* d_out, int out_size, void* d_ws, size_t ws_size,
                              hipStream_t stream){
  (void)in_sizes; (void)n_in; (void)out_size; (void)ws_size;
  const float* x  = (const float*)d_in[0];   // [64][512][512]
  const float* Wx = (const float*)d_in[1];   // [4][512][1024]
  const float* Wh = (const float*)d_in[2];   // [4][1024][1024]
  const float* b  = (const float*)d_in[3];   // [4][1024]
  char* ws = (char*)d_ws;
  unsigned short* pw      = (unsigned short*)ws;                    // 12,582,912 B packed weights
  unsigned short* xbf     = (unsigned short*)(ws + 12582912);       // 33,554,432 B x in bf16
  unsigned long long* hq  = (unsigned long long*)(ws + 46137344);   //    524,288 B tagged h double buffer
  float* out = (float*)d_out;

  k_convert_x<<<dim3(8192), dim3(256), 0, stream>>>(x, xbf);
  k_pack_w  <<<dim3(3072), dim3(256), 0, stream>>>(Wx, Wh, pw);
  k_scan    <<<dim3(256),  dim3(256), 0, stream>>>(pw, xbf, b, hq, out);
}

// Round 5
// 3604.734 us; speedup vs baseline: 1.9432x; 1.9432x over previous
//
#include <hip/hip_runtime.h>
#include <hip/hip_bf16.h>
#include <stdint.h>
#include <stddef.h>

// LSTM: INPUT=512, HIDDEN=1024, BATCH=64, SEQ=512.
// Persistent kernel, TAG-IN-DATA sync, v2 (fixed LDS conflicts + coalescing):
//   - h stored as (tag<<16)|bf16 tagged dwords, tag = exact step t. Producer:
//     2 fire-and-forget 8B agent stores per publishing lane (no vmcnt ack, no flag).
//   - Consumer: per thread 16 chunks of 16B, interleaved so each k-iteration the
//     16 threads of a row cohort read 256B contiguous (coalesced) and write 128B
//     contiguous packed bf16 to LDS (bank-conflict-free). Straight-line first
//     pass; retries reload only stale chunks.
//   - 2 barriers/step. x-side GEMM computed one step ahead, off the critical path.
//   - Weights pinned in registers (48 x short8 per wave).
#define ISZ   512
#define HSZ   1024
#define NBAT  64
#define SEQL  512

typedef __attribute__((ext_vector_type(8))) short  short8;   // 8 x bf16 (4 VGPR)
typedef __attribute__((ext_vector_type(4))) float  floatx4;  // MFMA accumulator

__device__ __forceinline__ unsigned short f2bf(float f){     // RNE f32 -> bf16
  unsigned int u = __float_as_uint(f);
  u += 0x7FFFu + ((u >> 16) & 1u);
  return (unsigned short)(u >> 16);
}
__device__ __forceinline__ float sigf(float x){ return 1.0f / (1.0f + __expf(-x)); }
__device__ __forceinline__ float tanh_(float x){ return 2.0f / (1.0f + __expf(-2.0f * x)) - 1.0f; }
__device__ __forceinline__ float sel4(int idx, float a0, float a1, float a2, float a3){
  float r01 = (idx & 1) ? a1 : a0;
  float r23 = (idx & 1) ? a3 : a2;
  return (idx & 2) ? r23 : r01;
}

// ---------------- x f32 -> bf16 ----------------
__global__ __launch_bounds__(256) void k_convert_x(const float* __restrict__ x,
                                                   unsigned short* __restrict__ xb){
  int i = (blockIdx.x * 256 + threadIdx.x) * 8;                      // 8192*256*8 == 64*512*512
  const float4* p = (const float4*)(x + i);
  float4 a = p[0], b = p[1];
  unsigned int w0 = (unsigned int)f2bf(a.x) | ((unsigned int)f2bf(a.y) << 16);
  unsigned int w1 = (unsigned int)f2bf(a.z) | ((unsigned int)f2bf(a.w) << 16);
  unsigned int w2 = (unsigned int)f2bf(b.x) | ((unsigned int)f2bf(b.y) << 16);
  unsigned int w3 = (unsigned int)f2bf(b.z) | ((unsigned int)f2bf(b.w) << 16);
  *(uint4*)(xb + i) = make_uint4(w0, w1, w2, w3);
}

// ---------------- pack W_h/W_x into per-(cg,wave,chunk,lane) B-fragments ----------------
__global__ __launch_bounds__(256) void k_pack_w(const float* __restrict__ Wx,
                                                const float* __restrict__ Wh,
                                                unsigned short* __restrict__ pw){
  int id = blockIdx.x * 256 + threadIdx.x;     // < 786432 = 64*4*48*64
  int lane = id & 63;
  int ch   = (id >> 6) % 48;
  int t2   = (id >> 6) / 48;                   // cg*4 + wv
  int wv = t2 & 3, cg = t2 >> 2;
  int nn = lane & 15, kgrp = lane >> 4;
  int g = nn >> 2, hcl = nn & 3;
  int colh = cg * 16 + wv * 4 + hcl;           // 0..1023
  unsigned short o[8];
  if (ch < 32){
    int k0 = ch * 32 + kgrp * 8;
#pragma unroll
    for (int j = 0; j < 8; ++j) o[j] = f2bf(Wh[(g * 1024 + k0 + j) * 1024 + colh]);
  } else {
    int k0 = (ch - 32) * 32 + kgrp * 8;
#pragma unroll
    for (int j = 0; j < 8; ++j) o[j] = f2bf(Wx[(g * 512 + k0 + j) * 1024 + colh]);
  }
  unsigned int w0 = (unsigned int)o[0] | ((unsigned int)o[1] << 16);
  unsigned int w1 = (unsigned int)o[2] | ((unsigned int)o[3] << 16);
  unsigned int w2 = (unsigned int)o[4] | ((unsigned int)o[5] << 16);
  unsigned int w3 = (unsigned int)o[6] | ((unsigned int)o[7] << 16);
  ((uint4*)pw)[id] = make_uint4(w0, w1, w2, w3);
}

// ---------------- persistent LSTM scan ----------------
__global__ __launch_bounds__(256, 1) void k_scan(const unsigned short* __restrict__ pw,
                                                 const unsigned short* __restrict__ xb,
                                                 const float* __restrict__ bias,
                                                 unsigned long long* __restrict__ hq,  // [2][64][1024] tagged dwords (as qwords)
                                                 float* __restrict__ out){             // h[64][1024] ++ c[64][1024]
  __shared__ __align__(16) char lds_h[16 * 2048];        // 16 batches x 1024 bf16, XOR-swizzled
  __shared__ __align__(16) char lds_x[16 * 1024];        // 16 batches x 512 bf16, XOR-swizzled

  const int wg = blockIdx.x;       // 0..255
  const int bg = wg >> 6;          // batch group 0..3 (independent chains)
  const int cg = wg & 63;          // col group 0..63
  const int tid = threadIdx.x;
  const int wv = tid >> 6;         // wave 0..3
  const int lane = tid & 63;
  const int b0 = bg * 16;

  // ---- persistent weights in registers, PINNED
  short8 bh[32], bx[16];
  {
    const uint4* base = (const uint4*)pw + (cg * 4 + wv) * 48 * 64 + lane;
#pragma unroll
    for (int c = 0; c < 32; ++c) bh[c] = *(const short8*)(base + c * 64);
#pragma unroll
    for (int c = 0; c < 16; ++c) bx[c] = *(const short8*)(base + (32 + c) * 64);
  }
#pragma unroll
  for (int c = 0; c < 32; ++c) asm volatile("" : "+v"(bh[c]));
#pragma unroll
  for (int c = 0; c < 16; ++c) asm volatile("" : "+v"(bx[c]));

  const int nn = lane & 15;        // MFMA col index n
  const int G  = nn >> 2;          // gate group (0=i,1=f,2=g,3=o)
  const int hc = nn & 3;           // h-col within wave
  const int kgrp = lane >> 4;      // k-group 0..3
  const int colh = cg * 16 + wv * 4 + hc;    // global h-col 0..1023
  const float b_i = bias[0 * HSZ + colh];
  const float b_f = bias[1 * HSZ + colh];
  const float b_g = bias[2 * HSZ + colh];
  const float b_o = bias[3 * HSZ + colh];

  // A-fragment LDS read bases
  const int arow = nn;                        // batch row 0..15
  const int swz  = (arow & 7) << 4;
  const int hb0  = arow * 2048 + ((kgrp * 16 +  0) ^ swz);
  const int hb1  = arow * 2048 + ((kgrp * 16 + 64) ^ swz);
  const int xq0  = arow * 1024 + ((kgrp * 16 +  0) ^ swz);
  const int xq1  = arow * 1024 + ((kgrp * 16 + 64) ^ swz);

  // consumer poll geometry: thread covers row (tid>>4); chunk k covers cols (tid&15)*4 + 64k
  const int prow = tid >> 4;
  const int psub = tid & 15;
  const int pswz = (prow & 7) << 4;

  float cst[4] = {0.f, 0.f, 0.f, 0.f};        // c-state: rows kgrp*4+r, col hc
  floatx4 xp0, xp1;                           // parked xg(t)

  // ---- prologue: stage x(0), compute xg(0)
  {
#pragma unroll
    for (int i = 0; i < 4; ++i){
      int ch = i * 256 + tid;
      int row = ch >> 6, o16 = ch & 63;
      uint4 v = *(const uint4*)((const char*)xb + (((size_t)(b0 + row) * SEQL + 0) * ISZ) * 2 + o16 * 16);
      *(uint4*)(lds_x + row * 1024 + ((o16 * 16) ^ ((row & 7) << 4))) = v;
    }
    __syncthreads();
    floatx4 a0v = {0.f,0.f,0.f,0.f}, a1v = {0.f,0.f,0.f,0.f};
#pragma unroll
    for (int q = 0; q < 8; ++q){
      short8 a0 = *(const short8*)(lds_x + xq0 + q * 128);
      a0v = __builtin_amdgcn_mfma_f32_16x16x32_bf16(a0, bx[2 * q], a0v, 0, 0, 0);
      short8 a1 = *(const short8*)(lds_x + xq1 + q * 128);
      a1v = __builtin_amdgcn_mfma_f32_16x16x32_bf16(a1, bx[2 * q + 1], a1v, 0, 0, 0);
    }
    xp0 = a0v; xp1 = a1v;
    __syncthreads();
  }

#pragma unroll 1
  for (int t = 0; t < SEQL; ++t){
    // ---- issue x loads for t+1 (latency hidden under the poll)
    const int tn = (t + 1 < SEQL) ? (t + 1) : (SEQL - 1);
    uint4 xr[4]; int xdst[4];
#pragma unroll
    for (int i = 0; i < 4; ++i){
      int ch = i * 256 + tid;
      int row = ch >> 6, o16 = ch & 63;
      xr[i] = *(const uint4*)((const char*)xb + (((size_t)(b0 + row) * SEQL + tn) * ISZ) * 2 + o16 * 16);
      xdst[i] = row * 1024 + ((o16 * 16) ^ ((row & 7) << 4));
    }

    // ---- poll h(t-1) directly (tag-validated), interleaved chunks, stage into lds_h
    if (t > 0){
      const unsigned int tg = (unsigned int)(t - 1);
      // qword base for this thread: row (b0+prow), qword index psub*2 (+ 32k per chunk)
      const unsigned long long* hb = hq + ((size_t)(((t - 1) & 1) * 64 + b0 + prow)) * 512 + psub * 2;
      unsigned long long qa[16], qb[16];
#pragma unroll
      for (int k = 0; k < 16; ++k){
        qa[k] = __hip_atomic_load(hb + 32 * k,     __ATOMIC_RELAXED, __HIP_MEMORY_SCOPE_AGENT);
        qb[k] = __hip_atomic_load(hb + 32 * k + 1, __ATOMIC_RELAXED, __HIP_MEMORY_SCOPE_AGENT);
      }
      unsigned int pend = 0xFFFFu;
      for (;;){
        unsigned int np = 0;
#pragma unroll
        for (int k = 0; k < 16; ++k){
          if ((pend >> k) & 1u){
            unsigned int a0 = (unsigned int)qa[k], a1 = (unsigned int)(qa[k] >> 32);
            unsigned int c0 = (unsigned int)qb[k], c1 = (unsigned int)(qb[k] >> 32);
            if ((((a0 >> 16) ^ tg) | ((a1 >> 16) ^ tg) | ((c0 >> 16) ^ tg) | ((c1 >> 16) ^ tg)) == 0u){
              unsigned long long packed =
                  (unsigned long long)((a0 & 0xFFFFu) | (a1 << 16)) |
                  ((unsigned long long)((c0 & 0xFFFFu) | (c1 << 16)) << 32);
              // cols (psub*4 + 64k)..+3 -> byte (psub*8 + 128k) ^ pswz : 16 threads x 8B contiguous
              *(unsigned long long*)(lds_h + prow * 2048 + ((psub * 8 + 128 * k) ^ pswz)) = packed;
            } else np |= (1u << k);
          }
        }
        if (!np) break;
        pend = np;
#pragma unroll
        for (int k = 0; k < 16; ++k){
          if ((pend >> k) & 1u){
            qa[k] = __hip_atomic_load(hb + 32 * k,     __ATOMIC_RELAXED, __HIP_MEMORY_SCOPE_AGENT);
            qb[k] = __hip_atomic_load(hb + 32 * k + 1, __ATOMIC_RELAXED, __HIP_MEMORY_SCOPE_AGENT);
          }
        }
      }
    }

    // ---- stage x(t+1) into lds_x (regs arrived during the poll)
#pragma unroll
    for (int i = 0; i < 4; ++i) *(uint4*)(lds_x + xdst[i]) = xr[i];
    __syncthreads();   // barrier 1: lds_h + lds_x ready

    // ---- gates: acc = parked xg(t); accumulate h-GEMM (K=1024)
    floatx4 acc0 = xp0, acc1 = xp1;
    if (t > 0){
#pragma unroll
      for (int q = 0; q < 16; ++q){
        short8 a0 = *(const short8*)(lds_h + hb0 + q * 128);
        acc0 = __builtin_amdgcn_mfma_f32_16x16x32_bf16(a0, bh[2 * q], acc0, 0, 0, 0);
        short8 a1 = *(const short8*)(lds_h + hb1 + q * 128);
        acc1 = __builtin_amdgcn_mfma_f32_16x16x32_bf16(a1, bh[2 * q + 1], acc1, 0, 0, 0);
      }
    }

    // ---- elementwise combine
    float hvv[4];
#pragma unroll
    for (int r = 0; r < 4; ++r){
      float own = acc0[r] + acc1[r];
      float s4  = __shfl_xor(own, 4);
      float s8  = __shfl_xor(own, 8);
      float s12 = __shfl_xor(own, 12);
      float pi = sel4(G,     own, s4, s8, s12) + b_i;
      float pf = sel4(G ^ 1, own, s4, s8, s12) + b_f;
      float pg = sel4(G ^ 2, own, s4, s8, s12) + b_g;
      float po = sel4(G ^ 3, own, s4, s8, s12) + b_o;
      float iv = sigf(pi), fv = sigf(pf), gv = tanh_(pg), ov = sigf(po);
      float cn = fv * cst[r] + iv * gv;
      cst[r] = cn;
      hvv[r] = ov * tanh_(cn);
      if (G == 0 && t == SEQL - 1){
        int gb = b0 + kgrp * 4 + r;
        out[gb * HSZ + colh] = hvv[r];                 // h_T
        out[NBAT * HSZ + gb * HSZ + colh] = cn;        // c_T
      }
    }

    // ---- publish h(t): 4x4 shfl transpose, then 2 tagged fire-and-forget 8B agent stores
    if (G == 0){
      float a0 = hvv[0], a1 = hvv[1], a2 = hvv[2], a3 = hvv[3];
      float s0 = __shfl_xor(a1, 1), s1 = __shfl_xor(a0, 1);
      float s2 = __shfl_xor(a3, 1), s3 = __shfl_xor(a2, 1);
      bool o1 = (nn & 1);
      float t0 = o1 ? s0 : a0,  t1 = o1 ? a1 : s1;
      float t2 = o1 ? s2 : a2,  t3 = o1 ? a3 : s3;
      float u0 = __shfl_xor(t2, 2), u1 = __shfl_xor(t3, 2);
      float u2 = __shfl_xor(t0, 2), u3 = __shfl_xor(t1, 2);
      bool o2 = (nn & 2);
      float w0 = o2 ? u0 : t0,  w1 = o2 ? u1 : t1;
      float w2 = o2 ? t2 : u2,  w3 = o2 ? t3 : u3;
      // lane nn holds row kgrp*4+nn, cols (cg*16+wv*4)+0..3
      unsigned int tagw = ((unsigned int)t) << 16;
      unsigned int p0 = (unsigned int)f2bf(w0) | tagw;
      unsigned int p1 = (unsigned int)f2bf(w1) | tagw;
      unsigned int p2 = (unsigned int)f2bf(w2) | tagw;
      unsigned int p3 = (unsigned int)f2bf(w3) | tagw;
      int row = kgrp * 4 + nn;
      size_t off = ((size_t)((t & 1) * 64 + b0 + row)) * 512 + (cg * 16 + wv * 4) / 2;
      __hip_atomic_store(hq + off,     (unsigned long long)p0 | ((unsigned long long)p1 << 32),
                         __ATOMIC_RELAXED, __HIP_MEMORY_SCOPE_AGENT);
      __hip_atomic_store(hq + off + 1, (unsigned long long)p2 | ((unsigned long long)p3 << 32),
                         __ATOMIC_RELAXED, __HIP_MEMORY_SCOPE_AGENT);
    }

    // ---- x-GEMM for t+1 (slack window, off the recurrent path)
    {
      floatx4 a0v = {0.f,0.f,0.f,0.f}, a1v = {0.f,0.f,0.f,0.f};
#pragma unroll
      for (int q = 0; q < 8; ++q){
        short8 a0 = *(const short8*)(lds_x + xq0 + q * 128);
        a0v = __builtin_amdgcn_mfma_f32_16x16x32_bf16(a0, bx[2 * q], a0v, 0, 0, 0);
        short8 a1 = *(const short8*)(lds_x + xq1 + q * 128);
        a1v = __builtin_amdgcn_mfma_f32_16x16x32_bf16(a1, bx[2 * q + 1], a1v, 0, 0, 0);
      }
      xp0 = a0v; xp1 = a1v;
    }
    __syncthreads();   // barrier 2: protects lds_h/lds_x reuse next iteration
  }
}

extern "C" void kernel_launch(void* const* d_in, const int* in_sizes, int n_in,
                              void* d_out, int out_size, void* d_ws, size_t ws_size,
                              hipStream_t stream){
  (void)in_sizes; (void)n_in; (void)out_size; (void)ws_size;
  const float* x  = (const float*)d_in[0];   // [64][512][512]
  const float* Wx = (const float*)d_in[1];   // [4][512][1024]
  const float* Wh = (const float*)d_in[2];   // [4][1024][1024]
  const float* b  = (const float*)d_in[3];   // [4][1024]
  char* ws = (char*)d_ws;
  unsigned short* pw      = (unsigned short*)ws;                    // 12,582,912 B packed weights
  unsigned short* xbf     = (unsigned short*)(ws + 12582912);       // 33,554,432 B x in bf16
  unsigned long long* hq  = (unsigned long long*)(ws + 46137344);   //    524,288 B tagged h double buffer
  float* out = (float*)d_out;

  k_convert_x<<<dim3(8192), dim3(256), 0, stream>>>(x, xbf);
  k_pack_w  <<<dim3(3072), dim3(256), 0, stream>>>(Wx, Wh, pw);
  k_scan    <<<dim3(256),  dim3(256), 0, stream>>>(pw, xbf, b, hq, out);
}